// Round 3
// baseline (2721.288 us; speedup 1.0000x reference)
//
#include <hip/hip_runtime.h>
#include <hip/hip_bf16.h>

#define NU 160000
#define NM 60000
#define DD 64
#define NE 5000000
#define NL 200000

// res = x + (1/2 + 1/3 + 1/4) * agg = x + (13/12)*agg  (all layers propagate layer-0)
#define COEF (13.0f / 12.0f)

#define SHIFT_U 9                               // 512 users/bucket
#define SHIFT_M 6                               // 64 movies/bucket (m-side gather buckets)
#define NBU ((NU + (1 << SHIFT_U) - 1) >> SHIFT_U)   // 313
#define NBM ((NM + (1 << SHIFT_M) - 1) >> SHIFT_M)   // 938
#define VB_U 16   // movie id fits 16 bits (60000 < 65536)
#define VB_M 18   // user id fits 18 bits (160000 < 262144)

// source blocking:
//  u-side: movie sources split 2 ways (h inner in key) -> rp spans contiguous, gather full row
//  m-side: user sources split 13 ways (h OUTER in key) -> phase-major gather with LDS accumulators
#define UDIV 30000        // movie block = movie / 30000  -> 0..1
#define LG_U 1
#define MDIV 13000        // user block = user / 13000    -> 0..12  (y_u slice <= 1.66 MB)
#define NPH_M 13
#define BS 1024           // virtual keys per bucket (both sides)
#define NVU2 (NBU << 10)  // 320512 virtual u-slots (bucket-major)
#define NVM2 (NBM << 10)  // 960512 virtual m-slots (bucket-major)

// ---------------- pass A: bucket counts only ----------------

#define CEC 16   // edges/thread

__global__ void bucket_count_kernel(const int* __restrict__ ef, const int* __restrict__ et,
                                    int* __restrict__ gbh_u, int* __restrict__ gbh_m) {
    __shared__ int bhu[NBU], bhm[NBM];
    int tid = threadIdx.x;
    for (int i = tid; i < NBU; i += 256) bhu[i] = 0;
    for (int i = tid; i < NBM; i += 256) bhm[i] = 0;
    __syncthreads();
    int base = (blockIdx.x * 256 + tid) * CEC;
    if (base < NE) {   // NE % 16 == 0 -> all-or-none
        const int4* f4 = (const int4*)(ef + base);
        const int4* t4 = (const int4*)(et + base);
        #pragma unroll
        for (int q = 0; q < CEC / 4; q++) {
            int4 ff = f4[q]; int4 tt = t4[q];
            atomicAdd(&bhm[ff.x >> SHIFT_M], 1); atomicAdd(&bhu[tt.x >> SHIFT_U], 1);
            atomicAdd(&bhm[ff.y >> SHIFT_M], 1); atomicAdd(&bhu[tt.y >> SHIFT_U], 1);
            atomicAdd(&bhm[ff.z >> SHIFT_M], 1); atomicAdd(&bhu[tt.z >> SHIFT_U], 1);
            atomicAdd(&bhm[ff.w >> SHIFT_M], 1); atomicAdd(&bhu[tt.w >> SHIFT_U], 1);
        }
    }
    __syncthreads();
    for (int i = tid; i < NBU; i += 256) if (bhu[i]) atomicAdd(&gbh_u[i], bhu[i]);
    for (int i = tid; i < NBM; i += 256) if (bhm[i]) atomicAdd(&gbh_m[i], bhm[i]);
}

// ---------------- small exclusive scan (n <= 1024); out[n]=total; cursor copy ----------------

__global__ void scan_small_kernel(const int* __restrict__ in, int* __restrict__ out,
                                  int* __restrict__ cur, int n) {
    __shared__ int buf[256];
    int tid = threadIdx.x;
    int idx = tid * 4;
    int v0 = (idx + 0 < n) ? in[idx + 0] : 0;
    int v1 = (idx + 1 < n) ? in[idx + 1] : 0;
    int v2 = (idx + 2 < n) ? in[idx + 2] : 0;
    int v3 = (idx + 3 < n) ? in[idx + 3] : 0;
    int s = v0 + v1 + v2 + v3;
    buf[tid] = s;
    __syncthreads();
    for (int off = 1; off < 256; off <<= 1) {
        int t = (tid >= off) ? buf[tid - off] : 0;
        __syncthreads();
        buf[tid] += t;
        __syncthreads();
    }
    int p = buf[tid] - s;
    if (idx + 0 < n) { out[idx + 0] = p; if (cur) cur[idx + 0] = p; p += v0; }
    if (idx + 1 < n) { out[idx + 1] = p; if (cur) cur[idx + 1] = p; p += v1; }
    if (idx + 2 < n) { out[idx + 2] = p; if (cur) cur[idx + 2] = p; p += v2; }
    if (idx + 3 < n) { out[idx + 3] = p; if (cur) cur[idx + 3] = p; p += v3; }
    if (tid == 255) out[n] = buf[255];
}

// ---------------- coarse partition into bucket-grouped staging (packed int32) ----------------
// mode 0 (u-side): key=user,  val=movie: lk = ((u&511)<<1) | (movie>=UDIV), bucket = u>>9
// mode 1 (m-side): key=movie, val=user:  lk = ((user/MDIV)<<6) | (movie&63), bucket = movie>>6

#define PEC 16   // edges/thread; 4096/block

__global__ void partition_kernel(const int* __restrict__ key, const int* __restrict__ val,
                                 int* __restrict__ bcur, int* __restrict__ stage,
                                 int nb, int shift, int valbits, int mode) {
    __shared__ int lh[1024];
    __shared__ int lbase[1024];
    int tid = threadIdx.x;
    for (int i = tid; i < nb; i += 256) lh[i] = 0;
    __syncthreads();
    int base = (blockIdx.x * 256 + tid) * PEC;
    int lk_[PEC], v_[PEC], br_[PEC];
    bool act = base < NE;   // NE % 16 == 0 -> all-or-none
    if (act) {
        int k_[PEC];
        const int4* k4 = (const int4*)(key + base);
        const int4* v4 = (const int4*)(val + base);
        #pragma unroll
        for (int q = 0; q < PEC / 4; q++) {
            int4 kk = k4[q]; int4 vv = v4[q];
            k_[q * 4 + 0] = kk.x; k_[q * 4 + 1] = kk.y; k_[q * 4 + 2] = kk.z; k_[q * 4 + 3] = kk.w;
            v_[q * 4 + 0] = vv.x; v_[q * 4 + 1] = vv.y; v_[q * 4 + 2] = vv.z; v_[q * 4 + 3] = vv.w;
        }
        #pragma unroll
        for (int q = 0; q < PEC; q++) {
            int k = k_[q];
            int lk;
            if (mode == 0) lk = ((k & 511) << 1) | (v_[q] >= UDIV ? 1 : 0);
            else           lk = ((int)((unsigned)v_[q] / MDIV) << 6) | (k & 63);
            lk_[q] = lk;
            int b = k >> shift;
            int r = atomicAdd(&lh[b], 1);       // rank within (block,bucket) < 4096
            br_[q] = (b << 13) | r;
        }
    }
    __syncthreads();
    for (int i = tid; i < nb; i += 256) lbase[i] = lh[i] ? atomicAdd(&bcur[i], lh[i]) : 0;
    __syncthreads();
    if (act) {
        #pragma unroll
        for (int q = 0; q < PEC; q++) {
            int b = br_[q] >> 13;
            int r = br_[q] & 8191;
            stage[lbase[b] + r] = (lk_[q] << valbits) | v_[q];
        }
    }
}

// ---------------- per-bucket build: rp+pay over virtual keys, all in LDS ----------------
// pay[pos] = (stage & vmask) | ((key & pmask) << valbits)   (m-side keeps movie_local in pay)

__global__ void build_kernel(const int* __restrict__ stage, const int* __restrict__ bo,
                             int* __restrict__ rp, int* __restrict__ pay,
                             int n, int valbits, int pmask) {
    __shared__ int cnt[BS];
    __shared__ int tmp[BS];
    int b = blockIdx.x;
    int tid = threadIdx.x;
    int base = b << 10;
    int nn = min(BS, n - base);
    int vmask = (1 << valbits) - 1;
    int s0 = bo[b];
    int s1 = bo[b + 1];

    for (int i = tid; i < BS; i += 256) cnt[i] = 0;
    __syncthreads();
    // pass 1: histogram over bucket-local virtual keys
    for (int e = s0 + tid; e < s1; e += 256)
        atomicAdd(&cnt[stage[e] >> valbits], 1);
    __syncthreads();
    int ov[4];
    #pragma unroll
    for (int q = 0; q < 4; q++) ov[q] = cnt[tid + q * 256];
    // inclusive scan (Hillis-Steele over 1024)
    for (int off = 1; off < BS; off <<= 1) {
        int t[4];
        #pragma unroll
        for (int q = 0; q < 4; q++) {
            int i = tid + q * 256;
            t[q] = (i >= off) ? cnt[i - off] : 0;
        }
        __syncthreads();
        #pragma unroll
        for (int q = 0; q < 4; q++) cnt[tid + q * 256] += t[q];
        __syncthreads();
    }
    #pragma unroll
    for (int q = 0; q < 4; q++) {
        int i = tid + q * 256;
        int excl = cnt[i] - ov[q];
        tmp[i] = s0 + excl;
        if (i < nn) rp[base + i] = s0 + excl;
    }
    if (b == 0 && tid == 0) rp[n] = NE;
    __syncthreads();
    // pass 2: place payloads via LDS cursors
    for (int e = s0 + tid; e < s1; e += 256) {
        int p = stage[e];
        int k = p >> valbits;
        int pos = atomicAdd(&tmp[k], 1);
        pay[pos] = (p & vmask) | ((k & pmask) << valbits);
    }
}

// ---------------- inv kernels (degree from rp diffs) ----------------

__global__ void inv_from_rp_kernel(const int* __restrict__ rp, float* __restrict__ inv,
                                   int n, int lg) {
    int i = blockIdx.x * blockDim.x + threadIdx.x;
    if (i < n) {
        int d = rp[(i + 1) << lg] - rp[i << lg];
        inv[i] = (d > 0) ? rsqrtf((float)d) : 0.0f;
    }
}

// m-side virtual layout: (bucket<<10) | (h<<6) | movie_local
__global__ void inv_m_from_rp_kernel(const int* __restrict__ rp, float* __restrict__ inv) {
    int f = blockIdx.x * blockDim.x + threadIdx.x;
    if (f < NM) {
        int base = ((f >> 6) << 10) | (f & 63);
        int d = 0;
        #pragma unroll
        for (int h = 0; h < NPH_M; h++) {
            int idx = base + (h << 6);
            d += rp[idx + 1] - rp[idx];
        }
        inv[f] = (d > 0) ? rsqrtf((float)d) : 0.0f;
    }
}

// ---------------- prescale: y = bf16(inv_src * x_src) ----------------

__global__ void prescale_kernel(const float* __restrict__ x, const float* __restrict__ inv,
                                __hip_bfloat16* __restrict__ y, int total) {
    int i = blockIdx.x * blockDim.x + threadIdx.x;
    if (i < total) {
        int node = i >> 6;
        y[i] = __float2bfloat16(inv[node] * x[i]);
    }
}

// ---------------- u-side gather: one wave per user, full row (spans both h sub-rows) ----------------

__global__ void gather_u_kernel(const int* __restrict__ rp, const int* __restrict__ pay,
                                const float* __restrict__ inv_dst,
                                const __hip_bfloat16* __restrict__ y_src,
                                const float* __restrict__ x_dst,
                                float* __restrict__ res, int n) {
    int tid = blockIdx.x * blockDim.x + threadIdx.x;
    int node = tid >> 6;
    int lane = threadIdx.x & 63;
    if (node >= n) return;
    int start = rp[node << LG_U];
    int end   = rp[(node + 1) << LG_U];
    float acc = 0.0f;
    for (int i = start; i < end; i += 64) {
        int cnt = min(end - i, 64);
        int nid = (lane < cnt) ? pay[i + lane] : 0;
        int j = 0;
        for (; j + 8 <= cnt; j += 8) {
            float a0 = __bfloat162float(y_src[__shfl(nid, j + 0, 64) * DD + lane]);
            float a1 = __bfloat162float(y_src[__shfl(nid, j + 1, 64) * DD + lane]);
            float a2 = __bfloat162float(y_src[__shfl(nid, j + 2, 64) * DD + lane]);
            float a3 = __bfloat162float(y_src[__shfl(nid, j + 3, 64) * DD + lane]);
            float a4 = __bfloat162float(y_src[__shfl(nid, j + 4, 64) * DD + lane]);
            float a5 = __bfloat162float(y_src[__shfl(nid, j + 5, 64) * DD + lane]);
            float a6 = __bfloat162float(y_src[__shfl(nid, j + 6, 64) * DD + lane]);
            float a7 = __bfloat162float(y_src[__shfl(nid, j + 7, 64) * DD + lane]);
            acc += ((a0 + a1) + (a2 + a3)) + ((a4 + a5) + (a6 + a7));
        }
        for (; j < cnt; j++) {
            int f0 = __shfl(nid, j, 64);
            acc += __bfloat162float(y_src[f0 * DD + lane]);
        }
    }
    int o = node * DD + lane;
    res[o] = x_dst[o] + COEF * inv_dst[node] * acc;
}

// ---------------- m-side gather: one workgroup per 64-movie bucket, phase-major (h outer),
// branch-free LDS atomic accumulation; sentinel row absorbs padding lanes ----------------

__global__ __launch_bounds__(512) void gather_m_kernel(
        const int* __restrict__ rp, const int* __restrict__ pay,
        const float* __restrict__ inv_dst,
        const __hip_bfloat16* __restrict__ y_src,
        const float* __restrict__ x_dst,
        float* __restrict__ res) {
    __shared__ float acc[65 * DD];   // 16.25 KB (row 64 = sentinel/dummy)
    int b = blockIdx.x;
    int tid = threadIdx.x;
    int wave = tid >> 6;             // 0..7
    int lane = tid & 63;
    for (int i = tid; i < 65 * DD; i += 512) acc[i] = 0.0f;
    __syncthreads();

    int vbase = b << 10;
    const int umask = (1 << VB_M) - 1;
    const int SENT = 64 << VB_M;     // dummy movie row 64, user 0 (L1-hot)
    for (int h = 0; h < NPH_M; h++) {
        int s0 = rp[vbase + (h << 6)];
        int s1 = rp[vbase + (h << 6) + 64];
        int total = s1 - s0;
        int per = (total + 7) >> 3;
        int e0 = s0 + wave * per;
        int e1 = min(e0 + per, s1);
        for (int i = e0; i < e1; i += 64) {
            int cnt = min(e1 - i, 64);
            int pv = (lane < cnt) ? pay[i + lane] : SENT;
            int jmax = (cnt + 15) & ~15;
            for (int j = 0; j < jmax; j += 16) {
                #pragma unroll
                for (int k = 0; k < 16; k++) {
                    int p = __shfl(pv, j + k, 64);
                    float a = __bfloat162float(y_src[(p & umask) * DD + lane]);
                    atomicAdd(&acc[(p >> VB_M) * DD + lane], a);
                }
            }
        }
        __syncthreads();   // keep waves phase-aligned (13 cheap barriers)
    }

    int mb = b << 6;
    int nn = min(64, NM - mb);
    int gbase = mb * DD;
    for (int i = tid; i < nn * DD; i += 512) {
        int f = mb + (i >> 6);
        res[gbase + i] = x_dst[gbase + i] + COEF * inv_dst[f] * acc[i];
    }
}

// ---------------- score ----------------

__global__ void score_kernel(const int* __restrict__ lm, const int* __restrict__ lu,
                             const float* __restrict__ ru, const float* __restrict__ rm,
                             float* __restrict__ scores) {
    int tid = blockIdx.x * blockDim.x + threadIdx.x;
    int l = tid >> 6;
    int d = threadIdx.x & 63;
    if (l < NL) {
        int u = lu[l];
        int m = lm[l];
        float v = ru[u * DD + d] * rm[m * DD + d];
        #pragma unroll
        for (int off = 32; off >= 1; off >>= 1)
            v += __shfl_down(v, off, 64);
        if (d == 0) scores[l] = v;
    }
}

// ---------------- fallback: atomic agg path ----------------

__global__ void degree_kernel_f(const int* __restrict__ ef, const int* __restrict__ et,
                                float* __restrict__ deg_m, float* __restrict__ deg_u) {
    int i = blockIdx.x * blockDim.x + threadIdx.x;
    if (i < NE) {
        atomicAdd(&deg_m[ef[i]], 1.0f);
        atomicAdd(&deg_u[et[i]], 1.0f);
    }
}

__global__ void inv_kernel_f(float* __restrict__ deg, int n) {
    int i = blockIdx.x * blockDim.x + threadIdx.x;
    if (i < n) {
        float d = deg[i];
        deg[i] = (d > 0.0f) ? (1.0f / sqrtf(d)) : 0.0f;
    }
}

__global__ void agg_kernel_f(const int* __restrict__ ef, const int* __restrict__ et,
                             const float* __restrict__ inv_m, const float* __restrict__ inv_u,
                             const float* __restrict__ x_u, const float* __restrict__ x_m,
                             float* __restrict__ res_u, float* __restrict__ res_m) {
    int tid = blockIdx.x * blockDim.x + threadIdx.x;
    int e = tid >> 6;
    int d = tid & 63;
    if (e < NE) {
        int f = ef[e];
        int t = et[e];
        float norm = inv_m[f] * inv_u[t] * COEF;
        atomicAdd(&res_u[t * DD + d], norm * x_m[f * DD + d]);
        atomicAdd(&res_m[f * DD + d], norm * x_u[t * DD + d]);
    }
}

__global__ void add_base_kernel_f(const float* __restrict__ xu, const float* __restrict__ xm,
                                  float* __restrict__ ru, float* __restrict__ rm) {
    int i = blockIdx.x * blockDim.x + threadIdx.x;
    const int nu = NU * DD;
    const int nm = NM * DD;
    if (i < nu) {
        ru[i] += xu[i];
    } else if (i < nu + nm) {
        int j = i - nu;
        rm[j] += xm[j];
    }
}

// ---------------- launch ----------------

extern "C" void kernel_launch(void* const* d_in, const int* in_sizes, int n_in,
                              void* d_out, int out_size, void* d_ws, size_t ws_size,
                              hipStream_t stream) {
    const float* emb_user  = (const float*)d_in[0];
    const float* emb_movie = (const float*)d_in[1];
    const int* edge_from   = (const int*)d_in[4];
    const int* edge_to     = (const int*)d_in[5];
    const int* label_movie = (const int*)d_in[6];
    const int* label_user  = (const int*)d_in[7];

    float* out    = (float*)d_out;
    float* scores = out;                              // [NL]
    float* res_u  = out + NL;                         // [NU*DD]
    float* res_m  = out + NL + (size_t)NU * DD;       // [NM*DD]

    // ws layout
    int*   gbh_u  = (int*)d_ws;                       // NBU  (zeroed)
    int*   gbh_m  = gbh_u + NBU;                      // NBM  (zeroed)
    int*   bo_u   = gbh_m + NBM;                      // NBU+1
    int*   bcur_u = bo_u + NBU + 1;                   // NBU
    int*   bo_m   = bcur_u + NBU;                     // NBM+1
    int*   bcur_m = bo_m + NBM + 1;                   // NBM
    float* inv_u  = (float*)(bcur_m + NBM);           // NU
    float* inv_m  = inv_u + NU;                       // NM
    int*   rp_u   = (int*)(inv_m + NM);               // NVU2+1
    int*   rp_m   = rp_u + NVU2 + 1;                  // NVM2+1
    int*   pay_u  = rp_m + NVM2 + 1;                  // NE
    int*   pay_m  = pay_u + NE;                       // NE
    // union region: stage (NE ints, dead after builds) then y_u/y_m (bf16)
    int*   ureg   = pay_m + NE;
    int*   stage  = ureg;                             // NE ints
    __hip_bfloat16* y_u = (__hip_bfloat16*)ureg;                      // NU*DD bf16
    __hip_bfloat16* y_m = (__hip_bfloat16*)(ureg + (size_t)NU * DD / 2); // NM*DD bf16

    size_t ysz    = (size_t)(NU + NM) * DD / 2;       // ints for y region
    size_t uni    = (size_t)NE > ysz ? (size_t)NE : ysz;
    size_t needed = ((size_t)(ureg - (int*)d_ws) + uni) * sizeof(int);

    if (ws_size >= needed) {
        hipMemsetAsync(gbh_u, 0, (size_t)(NBU + NBM) * sizeof(int), stream);

        bucket_count_kernel<<<(NE / CEC + 255) / 256, 256, 0, stream>>>(
            edge_from, edge_to, gbh_u, gbh_m);
        scan_small_kernel<<<1, 256, 0, stream>>>(gbh_u, bo_u, bcur_u, NBU);
        scan_small_kernel<<<1, 256, 0, stream>>>(gbh_m, bo_m, bcur_m, NBM);

        // u-side: dest = user (edge_to), src = movie (edge_from); h inner -> full-row gather
        partition_kernel<<<(NE / PEC + 255) / 256, 256, 0, stream>>>(
            edge_to, edge_from, bcur_u, stage, NBU, SHIFT_U, VB_U, 0);
        build_kernel<<<NBU, 256, 0, stream>>>(stage, bo_u, rp_u, pay_u, NVU2, VB_U, 0);

        // m-side: dest = movie (edge_from), src = user (edge_to); h OUTER -> phase-major gather
        partition_kernel<<<(NE / PEC + 255) / 256, 256, 0, stream>>>(
            edge_from, edge_to, bcur_m, stage, NBM, SHIFT_M, VB_M, 1);
        build_kernel<<<NBM, 256, 0, stream>>>(stage, bo_m, rp_m, pay_m, NVM2, VB_M, 63);

        // inv from rp diffs
        inv_from_rp_kernel<<<(NU + 255) / 256, 256, 0, stream>>>(rp_u, inv_u, NU, LG_U);
        inv_m_from_rp_kernel<<<(NM + 255) / 256, 256, 0, stream>>>(rp_m, inv_m);

        // prescale (stage is dead now; y overlays it)
        prescale_kernel<<<((size_t)NU * DD + 255) / 256, 256, 0, stream>>>(
            emb_user, inv_u, y_u, NU * DD);
        prescale_kernel<<<((size_t)NM * DD + 255) / 256, 256, 0, stream>>>(
            emb_movie, inv_m, y_m, NM * DD);

        gather_u_kernel<<<((size_t)NU * 64 + 255) / 256, 256, 0, stream>>>(
            rp_u, pay_u, inv_u, y_m, emb_user, res_u, NU);
        gather_m_kernel<<<NBM, 512, 0, stream>>>(
            rp_m, pay_m, inv_m, y_u, emb_movie, res_m);
    } else {
        // ---- fallback: atomic path ----
        float* fdeg_u = (float*)d_ws;
        float* fdeg_m = fdeg_u + NU;
        hipMemsetAsync(res_u, 0, (size_t)(NU + NM) * DD * sizeof(float), stream);
        hipMemsetAsync(fdeg_u, 0, (size_t)(NU + NM) * sizeof(float), stream);
        degree_kernel_f<<<(NE + 255) / 256, 256, 0, stream>>>(edge_from, edge_to, fdeg_m, fdeg_u);
        inv_kernel_f<<<(NU + NM + 255) / 256, 256, 0, stream>>>(fdeg_u, NU + NM);
        agg_kernel_f<<<((size_t)NE * 64 + 255) / 256, 256, 0, stream>>>(
            edge_from, edge_to, fdeg_m, fdeg_u, emb_user, emb_movie, res_u, res_m);
        add_base_kernel_f<<<((NU + NM) * DD + 255) / 256, 256, 0, stream>>>(
            emb_user, emb_movie, res_u, res_m);
    }

    score_kernel<<<((size_t)NL * 64 + 255) / 256, 256, 0, stream>>>(
        label_movie, label_user, res_u, res_m, scores);
}

// Round 4
// 1065.481 us; speedup vs baseline: 2.5540x; 2.5540x over previous
//
#include <hip/hip_runtime.h>
#include <hip/hip_bf16.h>

#define NU 160000
#define NM 60000
#define DD 64
#define NE 5000000
#define NL 200000

// res = x + (1/2 + 1/3 + 1/4) * agg = x + (13/12)*agg  (all layers propagate layer-0)
#define COEF (13.0f / 12.0f)

// ---- phase-major grouped layout ----
// u-side: wave owns GU=40 users; movie sources split in NPH_U=4 slices (1.92MB of y_m each)
// m-side: wave owns GM=20 movies; user sources split in NPH_M=10 slices (2.0MB of y_u each)
// virtual key vk = (group*NPH + h)*G + dest_local ; pay sorted by vk; gather loops h OUTER,
// register racc per run, ONE plain LDS add per run (wave-exclusive rows; no atomics).
#define GU 40
#define NPH_U 4
#define UDIV 15000                      // h_u = movie / 15000 -> 0..3
#define NGRP_U (NU / GU)                // 4000 (exact)
#define NVK_U (NGRP_U * NPH_U * GU)     // 640000
#define NBK_U ((NVK_U + 1023) >> 10)    // 625

#define GM 20
#define NPH_M 10
#define MDIV 16000                      // h_m = user / 16000 -> 0..9
#define NGRP_M (NM / GM)                // 3000 (exact)
#define NVK_M (NGRP_M * NPH_M * GM)     // 600000
#define NBK_M ((NVK_M + 1023) >> 10)    // 586

#define VB_U 16   // movie id fits 16 bits
#define VB_M 18   // user id fits 18 bits
#define BS 1024   // virtual keys per build bucket

// ---------------- pass A: bucket counts only ----------------

#define CEC 16   // edges/thread

__device__ __forceinline__ int vk_u_of(int u, int m) {
    return ((u / GU) * NPH_U + m / UDIV) * GU + (u % GU);
}
__device__ __forceinline__ int vk_m_of(int m, int u) {
    return ((m / GM) * NPH_M + u / MDIV) * GM + (m % GM);
}

__global__ void bucket_count_kernel(const int* __restrict__ ef, const int* __restrict__ et,
                                    int* __restrict__ gbh_u, int* __restrict__ gbh_m) {
    __shared__ int bhu[NBK_U], bhm[NBK_M];
    int tid = threadIdx.x;
    for (int i = tid; i < NBK_U; i += 256) bhu[i] = 0;
    for (int i = tid; i < NBK_M; i += 256) bhm[i] = 0;
    __syncthreads();
    int base = (blockIdx.x * 256 + tid) * CEC;
    if (base < NE) {   // NE % 16 == 0 -> all-or-none
        const int4* f4 = (const int4*)(ef + base);
        const int4* t4 = (const int4*)(et + base);
        #pragma unroll
        for (int q = 0; q < CEC / 4; q++) {
            int4 ff = f4[q]; int4 tt = t4[q];
            atomicAdd(&bhm[vk_m_of(ff.x, tt.x) >> 10], 1); atomicAdd(&bhu[vk_u_of(tt.x, ff.x) >> 10], 1);
            atomicAdd(&bhm[vk_m_of(ff.y, tt.y) >> 10], 1); atomicAdd(&bhu[vk_u_of(tt.y, ff.y) >> 10], 1);
            atomicAdd(&bhm[vk_m_of(ff.z, tt.z) >> 10], 1); atomicAdd(&bhu[vk_u_of(tt.z, ff.z) >> 10], 1);
            atomicAdd(&bhm[vk_m_of(ff.w, tt.w) >> 10], 1); atomicAdd(&bhu[vk_u_of(tt.w, ff.w) >> 10], 1);
        }
    }
    __syncthreads();
    for (int i = tid; i < NBK_U; i += 256) if (bhu[i]) atomicAdd(&gbh_u[i], bhu[i]);
    for (int i = tid; i < NBK_M; i += 256) if (bhm[i]) atomicAdd(&gbh_m[i], bhm[i]);
}

// ---------------- small exclusive scan (n <= 1024); out[n]=total; cursor copy ----------------

__global__ void scan_small_kernel(const int* __restrict__ in, int* __restrict__ out,
                                  int* __restrict__ cur, int n) {
    __shared__ int buf[256];
    int tid = threadIdx.x;
    int idx = tid * 4;
    int v0 = (idx + 0 < n) ? in[idx + 0] : 0;
    int v1 = (idx + 1 < n) ? in[idx + 1] : 0;
    int v2 = (idx + 2 < n) ? in[idx + 2] : 0;
    int v3 = (idx + 3 < n) ? in[idx + 3] : 0;
    int s = v0 + v1 + v2 + v3;
    buf[tid] = s;
    __syncthreads();
    for (int off = 1; off < 256; off <<= 1) {
        int t = (tid >= off) ? buf[tid - off] : 0;
        __syncthreads();
        buf[tid] += t;
        __syncthreads();
    }
    int p = buf[tid] - s;
    if (idx + 0 < n) { out[idx + 0] = p; if (cur) cur[idx + 0] = p; p += v0; }
    if (idx + 1 < n) { out[idx + 1] = p; if (cur) cur[idx + 1] = p; p += v1; }
    if (idx + 2 < n) { out[idx + 2] = p; if (cur) cur[idx + 2] = p; p += v2; }
    if (idx + 3 < n) { out[idx + 3] = p; if (cur) cur[idx + 3] = p; p += v3; }
    if (tid == 255) out[n] = buf[255];
}

// ---------------- coarse partition into bucket-grouped staging (packed int32) ----------------
// stage entry = ((vk & 1023) << valbits) | src

#define PEC 16   // edges/thread; 4096/block

__global__ void partition_kernel(const int* __restrict__ key, const int* __restrict__ val,
                                 int* __restrict__ bcur, int* __restrict__ stage,
                                 int nb, int valbits, int mode) {
    __shared__ int lh[1024];
    __shared__ int lbase[1024];
    int tid = threadIdx.x;
    for (int i = tid; i < nb; i += 256) lh[i] = 0;
    __syncthreads();
    int base = (blockIdx.x * 256 + tid) * PEC;
    int lk_[PEC], v_[PEC], br_[PEC];
    bool act = base < NE;   // NE % 16 == 0 -> all-or-none
    if (act) {
        int k_[PEC];
        const int4* k4 = (const int4*)(key + base);
        const int4* v4 = (const int4*)(val + base);
        #pragma unroll
        for (int q = 0; q < PEC / 4; q++) {
            int4 kk = k4[q]; int4 vv = v4[q];
            k_[q * 4 + 0] = kk.x; k_[q * 4 + 1] = kk.y; k_[q * 4 + 2] = kk.z; k_[q * 4 + 3] = kk.w;
            v_[q * 4 + 0] = vv.x; v_[q * 4 + 1] = vv.y; v_[q * 4 + 2] = vv.z; v_[q * 4 + 3] = vv.w;
        }
        #pragma unroll
        for (int q = 0; q < PEC; q++) {
            int vk = (mode == 0) ? vk_u_of(k_[q], v_[q]) : vk_m_of(k_[q], v_[q]);
            lk_[q] = vk & 1023;
            int b = vk >> 10;
            int r = atomicAdd(&lh[b], 1);       // rank within (block,bucket) < 4096
            br_[q] = (b << 13) | r;
        }
    }
    __syncthreads();
    for (int i = tid; i < nb; i += 256) lbase[i] = lh[i] ? atomicAdd(&bcur[i], lh[i]) : 0;
    __syncthreads();
    if (act) {
        #pragma unroll
        for (int q = 0; q < PEC; q++) {
            int b = br_[q] >> 13;
            int r = br_[q] & 8191;
            stage[lbase[b] + r] = (lk_[q] << valbits) | v_[q];
        }
    }
}

// ---------------- per-bucket build: rp+pay over virtual keys, all in LDS ----------------

__global__ void build_kernel(const int* __restrict__ stage, const int* __restrict__ bo,
                             int* __restrict__ rp, int* __restrict__ pay,
                             int n, int valbits) {
    __shared__ int cnt[BS];
    __shared__ int tmp[BS];
    int b = blockIdx.x;
    int tid = threadIdx.x;
    int base = b << 10;
    int nn = min(BS, n - base);
    int vmask = (1 << valbits) - 1;
    int s0 = bo[b];
    int s1 = bo[b + 1];

    for (int i = tid; i < BS; i += 256) cnt[i] = 0;
    __syncthreads();
    for (int e = s0 + tid; e < s1; e += 256)
        atomicAdd(&cnt[stage[e] >> valbits], 1);
    __syncthreads();
    int ov[4];
    #pragma unroll
    for (int q = 0; q < 4; q++) ov[q] = cnt[tid + q * 256];
    for (int off = 1; off < BS; off <<= 1) {
        int t[4];
        #pragma unroll
        for (int q = 0; q < 4; q++) {
            int i = tid + q * 256;
            t[q] = (i >= off) ? cnt[i - off] : 0;
        }
        __syncthreads();
        #pragma unroll
        for (int q = 0; q < 4; q++) cnt[tid + q * 256] += t[q];
        __syncthreads();
    }
    #pragma unroll
    for (int q = 0; q < 4; q++) {
        int i = tid + q * 256;
        int excl = cnt[i] - ov[q];
        tmp[i] = s0 + excl;
        if (i < nn) rp[base + i] = s0 + excl;
    }
    if (b == 0 && tid == 0) rp[n] = NE;
    __syncthreads();
    for (int e = s0 + tid; e < s1; e += 256) {
        int p = stage[e];
        int pos = atomicAdd(&tmp[p >> valbits], 1);
        pay[pos] = p & vmask;
    }
}

// ---------------- inv kernels (degree = sum of run lengths across phases) ----------------

__global__ void inv_u_kernel(const int* __restrict__ rp, float* __restrict__ inv) {
    int u = blockIdx.x * blockDim.x + threadIdx.x;
    if (u < NU) {
        int g = u / GU, i = u % GU;
        int d = 0;
        #pragma unroll
        for (int h = 0; h < NPH_U; h++) {
            int vk = (g * NPH_U + h) * GU + i;
            d += rp[vk + 1] - rp[vk];
        }
        inv[u] = (d > 0) ? rsqrtf((float)d) : 0.0f;
    }
}

__global__ void inv_m_kernel(const int* __restrict__ rp, float* __restrict__ inv) {
    int m = blockIdx.x * blockDim.x + threadIdx.x;
    if (m < NM) {
        int g = m / GM, i = m % GM;
        int d = 0;
        #pragma unroll
        for (int h = 0; h < NPH_M; h++) {
            int vk = (g * NPH_M + h) * GM + i;
            d += rp[vk + 1] - rp[vk];
        }
        inv[m] = (d > 0) ? rsqrtf((float)d) : 0.0f;
    }
}

// ---------------- prescale: y = bf16(inv_src * x_src) ----------------

__global__ void prescale_kernel(const float* __restrict__ x, const float* __restrict__ inv,
                                __hip_bfloat16* __restrict__ y, int total) {
    int i = blockIdx.x * blockDim.x + threadIdx.x;
    if (i < total) {
        int node = i >> 6;
        y[i] = __float2bfloat16(inv[node] * x[i]);
    }
}

// ---------------- phase-major gathers: h outer, register racc per run, one LDS add per run.
// All blocks co-resident -> chip-wide phase alignment -> per-phase y slice stays L2-hot. ----------------

__global__ __launch_bounds__(256) void gather_u_kernel(
        const int* __restrict__ rp, const int* __restrict__ pay,
        const float* __restrict__ inv_dst,
        const __hip_bfloat16* __restrict__ y_src,
        const float* __restrict__ x_dst,
        float* __restrict__ res) {
    __shared__ float accL[4 * GU * DD];   // 40 KB -> 4 blocks/CU; 1000 blocks all resident
    int wslot = threadIdx.x >> 6;
    int lane = threadIdx.x & 63;
    int W = blockIdx.x * 4 + wslot;       // group id, < NGRP_U
    float* myacc = &accL[(wslot * GU) * DD + lane];
    for (int i = 0; i < GU; i++) myacc[i * DD] = 0.0f;

    for (int h = 0; h < NPH_U; h++) {
        int vbase = (W * NPH_U + h) * GU;
        int rr = (lane <= GU) ? rp[vbase + lane] : 0;   // all 41 run boundaries in one load
        for (int i = 0; i < GU; i++) {
            int s = __shfl(rr, i, 64);
            int e = __shfl(rr, i + 1, 64);
            if (s == e) continue;
            float racc = 0.0f;
            for (int c = s; c < e; c += 64) {
                int cnt = min(e - c, 64);
                int nid = (lane < cnt) ? pay[c + lane] : 0;
                int j = 0;
                for (; j + 8 <= cnt; j += 8) {
                    float a0 = __bfloat162float(y_src[__shfl(nid, j + 0, 64) * DD + lane]);
                    float a1 = __bfloat162float(y_src[__shfl(nid, j + 1, 64) * DD + lane]);
                    float a2 = __bfloat162float(y_src[__shfl(nid, j + 2, 64) * DD + lane]);
                    float a3 = __bfloat162float(y_src[__shfl(nid, j + 3, 64) * DD + lane]);
                    float a4 = __bfloat162float(y_src[__shfl(nid, j + 4, 64) * DD + lane]);
                    float a5 = __bfloat162float(y_src[__shfl(nid, j + 5, 64) * DD + lane]);
                    float a6 = __bfloat162float(y_src[__shfl(nid, j + 6, 64) * DD + lane]);
                    float a7 = __bfloat162float(y_src[__shfl(nid, j + 7, 64) * DD + lane]);
                    racc += ((a0 + a1) + (a2 + a3)) + ((a4 + a5) + (a6 + a7));
                }
                for (; j < cnt; j++)
                    racc += __bfloat162float(y_src[__shfl(nid, j, 64) * DD + lane]);
            }
            myacc[i * DD] += racc;   // wave-exclusive plain LDS add, once per run
        }
    }

    int u0 = W * GU;
    for (int i = 0; i < GU; i++) {
        int u = u0 + i;
        int o = u * DD + lane;
        res[o] = x_dst[o] + COEF * inv_dst[u] * myacc[i * DD];
    }
}

__global__ __launch_bounds__(256) void gather_m_kernel(
        const int* __restrict__ rp, const int* __restrict__ pay,
        const float* __restrict__ inv_dst,
        const __hip_bfloat16* __restrict__ y_src,
        const float* __restrict__ x_dst,
        float* __restrict__ res) {
    __shared__ float accL[4 * GM * DD];   // 20 KB; 750 blocks all resident
    int wslot = threadIdx.x >> 6;
    int lane = threadIdx.x & 63;
    int W = blockIdx.x * 4 + wslot;       // group id, < NGRP_M
    float* myacc = &accL[(wslot * GM) * DD + lane];
    for (int i = 0; i < GM; i++) myacc[i * DD] = 0.0f;

    for (int h = 0; h < NPH_M; h++) {
        int vbase = (W * NPH_M + h) * GM;
        int rr = (lane <= GM) ? rp[vbase + lane] : 0;
        for (int i = 0; i < GM; i++) {
            int s = __shfl(rr, i, 64);
            int e = __shfl(rr, i + 1, 64);
            if (s == e) continue;
            float racc = 0.0f;
            for (int c = s; c < e; c += 64) {
                int cnt = min(e - c, 64);
                int nid = (lane < cnt) ? pay[c + lane] : 0;
                int j = 0;
                for (; j + 8 <= cnt; j += 8) {
                    float a0 = __bfloat162float(y_src[__shfl(nid, j + 0, 64) * DD + lane]);
                    float a1 = __bfloat162float(y_src[__shfl(nid, j + 1, 64) * DD + lane]);
                    float a2 = __bfloat162float(y_src[__shfl(nid, j + 2, 64) * DD + lane]);
                    float a3 = __bfloat162float(y_src[__shfl(nid, j + 3, 64) * DD + lane]);
                    float a4 = __bfloat162float(y_src[__shfl(nid, j + 4, 64) * DD + lane]);
                    float a5 = __bfloat162float(y_src[__shfl(nid, j + 5, 64) * DD + lane]);
                    float a6 = __bfloat162float(y_src[__shfl(nid, j + 6, 64) * DD + lane]);
                    float a7 = __bfloat162float(y_src[__shfl(nid, j + 7, 64) * DD + lane]);
                    racc += ((a0 + a1) + (a2 + a3)) + ((a4 + a5) + (a6 + a7));
                }
                for (; j < cnt; j++)
                    racc += __bfloat162float(y_src[__shfl(nid, j, 64) * DD + lane]);
            }
            myacc[i * DD] += racc;
        }
    }

    int m0 = W * GM;
    for (int i = 0; i < GM; i++) {
        int m = m0 + i;
        int o = m * DD + lane;
        res[o] = x_dst[o] + COEF * inv_dst[m] * myacc[i * DD];
    }
}

// ---------------- score ----------------

__global__ void score_kernel(const int* __restrict__ lm, const int* __restrict__ lu,
                             const float* __restrict__ ru, const float* __restrict__ rm,
                             float* __restrict__ scores) {
    int tid = blockIdx.x * blockDim.x + threadIdx.x;
    int l = tid >> 6;
    int d = threadIdx.x & 63;
    if (l < NL) {
        int u = lu[l];
        int m = lm[l];
        float v = ru[u * DD + d] * rm[m * DD + d];
        #pragma unroll
        for (int off = 32; off >= 1; off >>= 1)
            v += __shfl_down(v, off, 64);
        if (d == 0) scores[l] = v;
    }
}

// ---------------- fallback: atomic agg path ----------------

__global__ void degree_kernel_f(const int* __restrict__ ef, const int* __restrict__ et,
                                float* __restrict__ deg_m, float* __restrict__ deg_u) {
    int i = blockIdx.x * blockDim.x + threadIdx.x;
    if (i < NE) {
        atomicAdd(&deg_m[ef[i]], 1.0f);
        atomicAdd(&deg_u[et[i]], 1.0f);
    }
}

__global__ void inv_kernel_f(float* __restrict__ deg, int n) {
    int i = blockIdx.x * blockDim.x + threadIdx.x;
    if (i < n) {
        float d = deg[i];
        deg[i] = (d > 0.0f) ? (1.0f / sqrtf(d)) : 0.0f;
    }
}

__global__ void agg_kernel_f(const int* __restrict__ ef, const int* __restrict__ et,
                             const float* __restrict__ inv_m, const float* __restrict__ inv_u,
                             const float* __restrict__ x_u, const float* __restrict__ x_m,
                             float* __restrict__ res_u, float* __restrict__ res_m) {
    int tid = blockIdx.x * blockDim.x + threadIdx.x;
    int e = tid >> 6;
    int d = tid & 63;
    if (e < NE) {
        int f = ef[e];
        int t = et[e];
        float norm = inv_m[f] * inv_u[t] * COEF;
        atomicAdd(&res_u[t * DD + d], norm * x_m[f * DD + d]);
        atomicAdd(&res_m[f * DD + d], norm * x_u[t * DD + d]);
    }
}

__global__ void add_base_kernel_f(const float* __restrict__ xu, const float* __restrict__ xm,
                                  float* __restrict__ ru, float* __restrict__ rm) {
    int i = blockIdx.x * blockDim.x + threadIdx.x;
    const int nu = NU * DD;
    const int nm = NM * DD;
    if (i < nu) {
        ru[i] += xu[i];
    } else if (i < nu + nm) {
        int j = i - nu;
        rm[j] += xm[j];
    }
}

// ---------------- launch ----------------

extern "C" void kernel_launch(void* const* d_in, const int* in_sizes, int n_in,
                              void* d_out, int out_size, void* d_ws, size_t ws_size,
                              hipStream_t stream) {
    const float* emb_user  = (const float*)d_in[0];
    const float* emb_movie = (const float*)d_in[1];
    const int* edge_from   = (const int*)d_in[4];
    const int* edge_to     = (const int*)d_in[5];
    const int* label_movie = (const int*)d_in[6];
    const int* label_user  = (const int*)d_in[7];

    float* out    = (float*)d_out;
    float* scores = out;                              // [NL]
    float* res_u  = out + NL;                         // [NU*DD]
    float* res_m  = out + NL + (size_t)NU * DD;       // [NM*DD]

    // ws layout
    int*   gbh_u  = (int*)d_ws;                       // NBK_U (zeroed)
    int*   gbh_m  = gbh_u + NBK_U;                    // NBK_M (zeroed)
    int*   bo_u   = gbh_m + NBK_M;                    // NBK_U+1
    int*   bcur_u = bo_u + NBK_U + 1;                 // NBK_U
    int*   bo_m   = bcur_u + NBK_U;                   // NBK_M+1
    int*   bcur_m = bo_m + NBK_M + 1;                 // NBK_M
    float* inv_u  = (float*)(bcur_m + NBK_M);         // NU
    float* inv_m  = inv_u + NU;                       // NM
    int*   rp_u   = (int*)(inv_m + NM);               // NVK_U+1
    int*   rp_m   = rp_u + NVK_U + 1;                 // NVK_M+1
    int*   pay_u  = rp_m + NVK_M + 1;                 // NE
    int*   pay_m  = pay_u + NE;                       // NE
    // union region: stage (NE ints, dead after builds) then y_u/y_m (bf16)
    int*   ureg   = pay_m + NE;
    int*   stage  = ureg;                             // NE ints
    __hip_bfloat16* y_u = (__hip_bfloat16*)ureg;                      // NU*DD bf16
    __hip_bfloat16* y_m = (__hip_bfloat16*)(ureg + (size_t)NU * DD / 2); // NM*DD bf16

    size_t ysz    = (size_t)(NU + NM) * DD / 2;       // ints for y region
    size_t uni    = (size_t)NE > ysz ? (size_t)NE : ysz;
    size_t needed = ((size_t)(ureg - (int*)d_ws) + uni) * sizeof(int);

    if (ws_size >= needed) {
        hipMemsetAsync(gbh_u, 0, (size_t)(NBK_U + NBK_M) * sizeof(int), stream);

        bucket_count_kernel<<<(NE / CEC + 255) / 256, 256, 0, stream>>>(
            edge_from, edge_to, gbh_u, gbh_m);
        scan_small_kernel<<<1, 256, 0, stream>>>(gbh_u, bo_u, bcur_u, NBK_U);
        scan_small_kernel<<<1, 256, 0, stream>>>(gbh_m, bo_m, bcur_m, NBK_M);

        // u-side: dest = user (edge_to), src = movie (edge_from)
        partition_kernel<<<(NE / PEC + 255) / 256, 256, 0, stream>>>(
            edge_to, edge_from, bcur_u, stage, NBK_U, VB_U, 0);
        build_kernel<<<NBK_U, 256, 0, stream>>>(stage, bo_u, rp_u, pay_u, NVK_U, VB_U);

        // m-side: dest = movie (edge_from), src = user (edge_to)
        partition_kernel<<<(NE / PEC + 255) / 256, 256, 0, stream>>>(
            edge_from, edge_to, bcur_m, stage, NBK_M, VB_M, 1);
        build_kernel<<<NBK_M, 256, 0, stream>>>(stage, bo_m, rp_m, pay_m, NVK_M, VB_M);

        // inv from rp run-length sums
        inv_u_kernel<<<(NU + 255) / 256, 256, 0, stream>>>(rp_u, inv_u);
        inv_m_kernel<<<(NM + 255) / 256, 256, 0, stream>>>(rp_m, inv_m);

        // prescale (stage is dead now; y overlays it)
        prescale_kernel<<<((size_t)NU * DD + 255) / 256, 256, 0, stream>>>(
            emb_user, inv_u, y_u, NU * DD);
        prescale_kernel<<<((size_t)NM * DD + 255) / 256, 256, 0, stream>>>(
            emb_movie, inv_m, y_m, NM * DD);

        gather_u_kernel<<<NGRP_U / 4, 256, 0, stream>>>(
            rp_u, pay_u, inv_u, y_m, emb_user, res_u);
        gather_m_kernel<<<NGRP_M / 4, 256, 0, stream>>>(
            rp_m, pay_m, inv_m, y_u, emb_movie, res_m);
    } else {
        // ---- fallback: atomic path ----
        float* fdeg_u = (float*)d_ws;
        float* fdeg_m = fdeg_u + NU;
        hipMemsetAsync(res_u, 0, (size_t)(NU + NM) * DD * sizeof(float), stream);
        hipMemsetAsync(fdeg_u, 0, (size_t)(NU + NM) * sizeof(float), stream);
        degree_kernel_f<<<(NE + 255) / 256, 256, 0, stream>>>(edge_from, edge_to, fdeg_m, fdeg_u);
        inv_kernel_f<<<(NU + NM + 255) / 256, 256, 0, stream>>>(fdeg_u, NU + NM);
        agg_kernel_f<<<((size_t)NE * 64 + 255) / 256, 256, 0, stream>>>(
            edge_from, edge_to, fdeg_m, fdeg_u, emb_user, emb_movie, res_u, res_m);
        add_base_kernel_f<<<((NU + NM) * DD + 255) / 256, 256, 0, stream>>>(
            emb_user, emb_movie, res_u, res_m);
    }

    score_kernel<<<((size_t)NL * 64 + 255) / 256, 256, 0, stream>>>(
        label_movie, label_user, res_u, res_m, scores);
}

// Round 5
// 773.798 us; speedup vs baseline: 3.5168x; 1.3769x over previous
//
#include <hip/hip_runtime.h>
#include <hip/hip_bf16.h>

#define NU 160000
#define NM 60000
#define DD 64
#define NE 5000000
#define NL 200000

// res = x + (1/2 + 1/3 + 1/4) * agg = x + (13/12)*agg  (all layers propagate layer-0)
#define COEF (13.0f / 12.0f)

// ---- phase-major grouped layout ----
// u-side: wave owns GU=20 users; movie sources split in NPH_U=4 slices (1.92MB of y_m each)
// m-side: wave owns GM=8 movies;  user sources split in NPH_M=10 slices (2.0MB of y_u each)
// vk = (group*NPH + h)*G + dest_local ; pay sorted by vk; gather loops h OUTER with
// register racc per run, one plain LDS add per run; pay read in double-buffered 64-edge windows.
#define GU 20
#define NPH_U 4
#define UDIV 15000                      // h_u = movie / 15000 -> 0..3
#define NGRP_U (NU / GU)                // 8000 (exact)
#define NVK_U (NGRP_U * NPH_U * GU)     // 640000
#define NBK_U ((NVK_U + 1023) >> 10)    // 625

#define GM 8
#define NPH_M 10
#define MDIV 16000                      // h_m = user / 16000 -> 0..9
#define NGRP_M (NM / GM)                // 7500 (exact)
#define NVK_M (NGRP_M * NPH_M * GM)     // 600000
#define NBK_M ((NVK_M + 1023) >> 10)    // 586

#define VB_U 16   // movie id fits 16 bits
#define VB_M 18   // user id fits 18 bits
#define BS 1024   // virtual keys per build bucket

// ---------------- pass A: bucket counts only ----------------

#define CEC 16   // edges/thread

__device__ __forceinline__ int vk_u_of(int u, int m) {
    return ((u / GU) * NPH_U + m / UDIV) * GU + (u % GU);
}
__device__ __forceinline__ int vk_m_of(int m, int u) {
    return (((m >> 3) * NPH_M) + u / MDIV) * GM + (m & 7);
}

__global__ void bucket_count_kernel(const int* __restrict__ ef, const int* __restrict__ et,
                                    int* __restrict__ gbh_u, int* __restrict__ gbh_m) {
    __shared__ int bhu[NBK_U], bhm[NBK_M];
    int tid = threadIdx.x;
    for (int i = tid; i < NBK_U; i += 256) bhu[i] = 0;
    for (int i = tid; i < NBK_M; i += 256) bhm[i] = 0;
    __syncthreads();
    int base = (blockIdx.x * 256 + tid) * CEC;
    if (base < NE) {   // NE % 16 == 0 -> all-or-none
        const int4* f4 = (const int4*)(ef + base);
        const int4* t4 = (const int4*)(et + base);
        #pragma unroll
        for (int q = 0; q < CEC / 4; q++) {
            int4 ff = f4[q]; int4 tt = t4[q];
            atomicAdd(&bhm[vk_m_of(ff.x, tt.x) >> 10], 1); atomicAdd(&bhu[vk_u_of(tt.x, ff.x) >> 10], 1);
            atomicAdd(&bhm[vk_m_of(ff.y, tt.y) >> 10], 1); atomicAdd(&bhu[vk_u_of(tt.y, ff.y) >> 10], 1);
            atomicAdd(&bhm[vk_m_of(ff.z, tt.z) >> 10], 1); atomicAdd(&bhu[vk_u_of(tt.z, ff.z) >> 10], 1);
            atomicAdd(&bhm[vk_m_of(ff.w, tt.w) >> 10], 1); atomicAdd(&bhu[vk_u_of(tt.w, ff.w) >> 10], 1);
        }
    }
    __syncthreads();
    for (int i = tid; i < NBK_U; i += 256) if (bhu[i]) atomicAdd(&gbh_u[i], bhu[i]);
    for (int i = tid; i < NBK_M; i += 256) if (bhm[i]) atomicAdd(&gbh_m[i], bhm[i]);
}

// ---------------- small exclusive scan (n <= 1024); out[n]=total; cursor copy ----------------

__global__ void scan_small_kernel(const int* __restrict__ in, int* __restrict__ out,
                                  int* __restrict__ cur, int n) {
    __shared__ int buf[256];
    int tid = threadIdx.x;
    int idx = tid * 4;
    int v0 = (idx + 0 < n) ? in[idx + 0] : 0;
    int v1 = (idx + 1 < n) ? in[idx + 1] : 0;
    int v2 = (idx + 2 < n) ? in[idx + 2] : 0;
    int v3 = (idx + 3 < n) ? in[idx + 3] : 0;
    int s = v0 + v1 + v2 + v3;
    buf[tid] = s;
    __syncthreads();
    for (int off = 1; off < 256; off <<= 1) {
        int t = (tid >= off) ? buf[tid - off] : 0;
        __syncthreads();
        buf[tid] += t;
        __syncthreads();
    }
    int p = buf[tid] - s;
    if (idx + 0 < n) { out[idx + 0] = p; if (cur) cur[idx + 0] = p; p += v0; }
    if (idx + 1 < n) { out[idx + 1] = p; if (cur) cur[idx + 1] = p; p += v1; }
    if (idx + 2 < n) { out[idx + 2] = p; if (cur) cur[idx + 2] = p; p += v2; }
    if (idx + 3 < n) { out[idx + 3] = p; if (cur) cur[idx + 3] = p; p += v3; }
    if (tid == 255) out[n] = buf[255];
}

// ---------------- coarse partition into bucket-grouped staging (packed int32) ----------------
// stage entry = ((vk & 1023) << valbits) | src

#define PEC 16   // edges/thread; 4096/block

__global__ void partition_kernel(const int* __restrict__ key, const int* __restrict__ val,
                                 int* __restrict__ bcur, int* __restrict__ stage,
                                 int nb, int valbits, int mode) {
    __shared__ int lh[1024];
    __shared__ int lbase[1024];
    int tid = threadIdx.x;
    for (int i = tid; i < nb; i += 256) lh[i] = 0;
    __syncthreads();
    int base = (blockIdx.x * 256 + tid) * PEC;
    int lk_[PEC], v_[PEC], br_[PEC];
    bool act = base < NE;   // NE % 16 == 0 -> all-or-none
    if (act) {
        int k_[PEC];
        const int4* k4 = (const int4*)(key + base);
        const int4* v4 = (const int4*)(val + base);
        #pragma unroll
        for (int q = 0; q < PEC / 4; q++) {
            int4 kk = k4[q]; int4 vv = v4[q];
            k_[q * 4 + 0] = kk.x; k_[q * 4 + 1] = kk.y; k_[q * 4 + 2] = kk.z; k_[q * 4 + 3] = kk.w;
            v_[q * 4 + 0] = vv.x; v_[q * 4 + 1] = vv.y; v_[q * 4 + 2] = vv.z; v_[q * 4 + 3] = vv.w;
        }
        #pragma unroll
        for (int q = 0; q < PEC; q++) {
            int vk = (mode == 0) ? vk_u_of(k_[q], v_[q]) : vk_m_of(k_[q], v_[q]);
            lk_[q] = vk & 1023;
            int b = vk >> 10;
            int r = atomicAdd(&lh[b], 1);       // rank within (block,bucket) < 4096
            br_[q] = (b << 13) | r;
        }
    }
    __syncthreads();
    for (int i = tid; i < nb; i += 256) lbase[i] = lh[i] ? atomicAdd(&bcur[i], lh[i]) : 0;
    __syncthreads();
    if (act) {
        #pragma unroll
        for (int q = 0; q < PEC; q++) {
            int b = br_[q] >> 13;
            int r = br_[q] & 8191;
            stage[lbase[b] + r] = (lk_[q] << valbits) | v_[q];
        }
    }
}

// ---------------- per-bucket build: rp+pay over virtual keys, all in LDS ----------------

__global__ void build_kernel(const int* __restrict__ stage, const int* __restrict__ bo,
                             int* __restrict__ rp, int* __restrict__ pay,
                             int n, int valbits) {
    __shared__ int cnt[BS];
    __shared__ int tmp[BS];
    int b = blockIdx.x;
    int tid = threadIdx.x;
    int base = b << 10;
    int nn = min(BS, n - base);
    int vmask = (1 << valbits) - 1;
    int s0 = bo[b];
    int s1 = bo[b + 1];

    for (int i = tid; i < BS; i += 256) cnt[i] = 0;
    __syncthreads();
    for (int e = s0 + tid; e < s1; e += 256)
        atomicAdd(&cnt[stage[e] >> valbits], 1);
    __syncthreads();
    int ov[4];
    #pragma unroll
    for (int q = 0; q < 4; q++) ov[q] = cnt[tid + q * 256];
    for (int off = 1; off < BS; off <<= 1) {
        int t[4];
        #pragma unroll
        for (int q = 0; q < 4; q++) {
            int i = tid + q * 256;
            t[q] = (i >= off) ? cnt[i - off] : 0;
        }
        __syncthreads();
        #pragma unroll
        for (int q = 0; q < 4; q++) cnt[tid + q * 256] += t[q];
        __syncthreads();
    }
    #pragma unroll
    for (int q = 0; q < 4; q++) {
        int i = tid + q * 256;
        int excl = cnt[i] - ov[q];
        tmp[i] = s0 + excl;
        if (i < nn) rp[base + i] = s0 + excl;
    }
    if (b == 0 && tid == 0) rp[n] = NE;
    __syncthreads();
    for (int e = s0 + tid; e < s1; e += 256) {
        int p = stage[e];
        int pos = atomicAdd(&tmp[p >> valbits], 1);
        pay[pos] = p & vmask;
    }
}

// ---------------- inv kernels (degree = sum of run lengths across phases) ----------------

__global__ void inv_u_kernel(const int* __restrict__ rp, float* __restrict__ inv) {
    int u = blockIdx.x * blockDim.x + threadIdx.x;
    if (u < NU) {
        int g = u / GU, i = u % GU;
        int d = 0;
        #pragma unroll
        for (int h = 0; h < NPH_U; h++) {
            int vk = (g * NPH_U + h) * GU + i;
            d += rp[vk + 1] - rp[vk];
        }
        inv[u] = (d > 0) ? rsqrtf((float)d) : 0.0f;
    }
}

__global__ void inv_m_kernel(const int* __restrict__ rp, float* __restrict__ inv) {
    int m = blockIdx.x * blockDim.x + threadIdx.x;
    if (m < NM) {
        int g = m >> 3, i = m & 7;
        int d = 0;
        #pragma unroll
        for (int h = 0; h < NPH_M; h++) {
            int vk = (g * NPH_M + h) * GM + i;
            d += rp[vk + 1] - rp[vk];
        }
        inv[m] = (d > 0) ? rsqrtf((float)d) : 0.0f;
    }
}

// ---------------- prescale: y = bf16(inv_src * x_src) ----------------

__global__ void prescale_kernel(const float* __restrict__ x, const float* __restrict__ inv,
                                __hip_bfloat16* __restrict__ y, int total) {
    int i = blockIdx.x * blockDim.x + threadIdx.x;
    if (i < total) {
        int node = i >> 6;
        y[i] = __float2bfloat16(inv[node] * x[i]);
    }
}

// ---------------- phase-major gather: h outer, double-buffered 64-edge pay windows,
// 8-deep batched row loads, register racc per run, one plain LDS add per run. ----------------

template <int G, int NPH>
__global__ __launch_bounds__(256, 8) void gather_kernel_t(
        const int* __restrict__ rp, const int* __restrict__ pay,
        const float* __restrict__ inv_dst,
        const __hip_bfloat16* __restrict__ y_src,
        const float* __restrict__ x_dst,
        float* __restrict__ res) {
    __shared__ float accL[4 * G * DD];
    int wslot = threadIdx.x >> 6;
    int lane = threadIdx.x & 63;
    int W = blockIdx.x * 4 + wslot;       // group id (grid sized exactly)
    float* myacc = &accL[wslot * G * DD + lane];
    for (int i = 0; i < G; i++) myacc[i * DD] = 0.0f;

    int rr = 0;
    if (lane <= G) rr = rp[(W * NPH) * G + lane];
    for (int h = 0; h < NPH; h++) {
        int rrn = 0;
        if (h + 1 < NPH && lane <= G) rrn = rp[(W * NPH + h + 1) * G + lane];   // prefetch next phase
        int sph = __shfl(rr, 0, 64);
        int eph = __shfl(rr, G, 64);
        int wbase = sph;
        int pv  = (wbase + lane      < eph) ? pay[wbase + lane]      : 0;
        int pv2 = (wbase + 64 + lane < eph) ? pay[wbase + 64 + lane] : 0;      // prefetch next window
        for (int i = 0; i < G; i++) {
            int s = __shfl(rr, i, 64);
            int e = __shfl(rr, i + 1, 64);
            float racc = 0.0f;
            while (s < e) {
                if (s >= wbase + 64) {          // advance window (contiguous -> one step)
                    wbase += 64;
                    pv = pv2;
                    pv2 = (wbase + 64 + lane < eph) ? pay[wbase + 64 + lane] : 0;
                }
                int tend = min(e, wbase + 64);
                int j = s;
                for (; j + 8 <= tend; j += 8) {
                    int r = j - wbase;
                    int p0 = __shfl(pv, r + 0, 64);
                    int p1 = __shfl(pv, r + 1, 64);
                    int p2 = __shfl(pv, r + 2, 64);
                    int p3 = __shfl(pv, r + 3, 64);
                    int p4 = __shfl(pv, r + 4, 64);
                    int p5 = __shfl(pv, r + 5, 64);
                    int p6 = __shfl(pv, r + 6, 64);
                    int p7 = __shfl(pv, r + 7, 64);
                    float a0 = __bfloat162float(y_src[p0 * DD + lane]);
                    float a1 = __bfloat162float(y_src[p1 * DD + lane]);
                    float a2 = __bfloat162float(y_src[p2 * DD + lane]);
                    float a3 = __bfloat162float(y_src[p3 * DD + lane]);
                    float a4 = __bfloat162float(y_src[p4 * DD + lane]);
                    float a5 = __bfloat162float(y_src[p5 * DD + lane]);
                    float a6 = __bfloat162float(y_src[p6 * DD + lane]);
                    float a7 = __bfloat162float(y_src[p7 * DD + lane]);
                    racc += ((a0 + a1) + (a2 + a3)) + ((a4 + a5) + (a6 + a7));
                }
                if (j + 4 <= tend) {
                    int r = j - wbase;
                    int p0 = __shfl(pv, r + 0, 64);
                    int p1 = __shfl(pv, r + 1, 64);
                    int p2 = __shfl(pv, r + 2, 64);
                    int p3 = __shfl(pv, r + 3, 64);
                    float a0 = __bfloat162float(y_src[p0 * DD + lane]);
                    float a1 = __bfloat162float(y_src[p1 * DD + lane]);
                    float a2 = __bfloat162float(y_src[p2 * DD + lane]);
                    float a3 = __bfloat162float(y_src[p3 * DD + lane]);
                    racc += (a0 + a1) + (a2 + a3);
                    j += 4;
                }
                for (; j < tend; j++)
                    racc += __bfloat162float(y_src[__shfl(pv, j - wbase, 64) * DD + lane]);
                s = tend;
            }
            myacc[i * DD] += racc;
        }
        rr = rrn;
    }

    int g0 = W * G;
    for (int i = 0; i < G; i++) {
        int n = g0 + i;
        int o = n * DD + lane;
        res[o] = x_dst[o] + COEF * inv_dst[n] * myacc[i * DD];
    }
}

// ---------------- score ----------------

__global__ void score_kernel(const int* __restrict__ lm, const int* __restrict__ lu,
                             const float* __restrict__ ru, const float* __restrict__ rm,
                             float* __restrict__ scores) {
    int tid = blockIdx.x * blockDim.x + threadIdx.x;
    int l = tid >> 6;
    int d = threadIdx.x & 63;
    if (l < NL) {
        int u = lu[l];
        int m = lm[l];
        float v = ru[u * DD + d] * rm[m * DD + d];
        #pragma unroll
        for (int off = 32; off >= 1; off >>= 1)
            v += __shfl_down(v, off, 64);
        if (d == 0) scores[l] = v;
    }
}

// ---------------- fallback: atomic agg path ----------------

__global__ void degree_kernel_f(const int* __restrict__ ef, const int* __restrict__ et,
                                float* __restrict__ deg_m, float* __restrict__ deg_u) {
    int i = blockIdx.x * blockDim.x + threadIdx.x;
    if (i < NE) {
        atomicAdd(&deg_m[ef[i]], 1.0f);
        atomicAdd(&deg_u[et[i]], 1.0f);
    }
}

__global__ void inv_kernel_f(float* __restrict__ deg, int n) {
    int i = blockIdx.x * blockDim.x + threadIdx.x;
    if (i < n) {
        float d = deg[i];
        deg[i] = (d > 0.0f) ? (1.0f / sqrtf(d)) : 0.0f;
    }
}

__global__ void agg_kernel_f(const int* __restrict__ ef, const int* __restrict__ et,
                             const float* __restrict__ inv_m, const float* __restrict__ inv_u,
                             const float* __restrict__ x_u, const float* __restrict__ x_m,
                             float* __restrict__ res_u, float* __restrict__ res_m) {
    int tid = blockIdx.x * blockDim.x + threadIdx.x;
    int e = tid >> 6;
    int d = tid & 63;
    if (e < NE) {
        int f = ef[e];
        int t = et[e];
        float norm = inv_m[f] * inv_u[t] * COEF;
        atomicAdd(&res_u[t * DD + d], norm * x_m[f * DD + d]);
        atomicAdd(&res_m[f * DD + d], norm * x_u[t * DD + d]);
    }
}

__global__ void add_base_kernel_f(const float* __restrict__ xu, const float* __restrict__ xm,
                                  float* __restrict__ ru, float* __restrict__ rm) {
    int i = blockIdx.x * blockDim.x + threadIdx.x;
    const int nu = NU * DD;
    const int nm = NM * DD;
    if (i < nu) {
        ru[i] += xu[i];
    } else if (i < nu + nm) {
        int j = i - nu;
        rm[j] += xm[j];
    }
}

// ---------------- launch ----------------

extern "C" void kernel_launch(void* const* d_in, const int* in_sizes, int n_in,
                              void* d_out, int out_size, void* d_ws, size_t ws_size,
                              hipStream_t stream) {
    const float* emb_user  = (const float*)d_in[0];
    const float* emb_movie = (const float*)d_in[1];
    const int* edge_from   = (const int*)d_in[4];
    const int* edge_to     = (const int*)d_in[5];
    const int* label_movie = (const int*)d_in[6];
    const int* label_user  = (const int*)d_in[7];

    float* out    = (float*)d_out;
    float* scores = out;                              // [NL]
    float* res_u  = out + NL;                         // [NU*DD]
    float* res_m  = out + NL + (size_t)NU * DD;       // [NM*DD]

    // ws layout
    int*   gbh_u  = (int*)d_ws;                       // NBK_U (zeroed)
    int*   gbh_m  = gbh_u + NBK_U;                    // NBK_M (zeroed)
    int*   bo_u   = gbh_m + NBK_M;                    // NBK_U+1
    int*   bcur_u = bo_u + NBK_U + 1;                 // NBK_U
    int*   bo_m   = bcur_u + NBK_U;                   // NBK_M+1
    int*   bcur_m = bo_m + NBK_M + 1;                 // NBK_M
    float* inv_u  = (float*)(bcur_m + NBK_M);         // NU
    float* inv_m  = inv_u + NU;                       // NM
    int*   rp_u   = (int*)(inv_m + NM);               // NVK_U+1
    int*   rp_m   = rp_u + NVK_U + 1;                 // NVK_M+1
    int*   pay_u  = rp_m + NVK_M + 1;                 // NE
    int*   pay_m  = pay_u + NE;                       // NE
    // union region: stage (NE ints, dead after builds) then y_u/y_m (bf16)
    int*   ureg   = pay_m + NE;
    int*   stage  = ureg;                             // NE ints
    __hip_bfloat16* y_u = (__hip_bfloat16*)ureg;                      // NU*DD bf16
    __hip_bfloat16* y_m = (__hip_bfloat16*)(ureg + (size_t)NU * DD / 2); // NM*DD bf16

    size_t ysz    = (size_t)(NU + NM) * DD / 2;       // ints for y region
    size_t uni    = (size_t)NE > ysz ? (size_t)NE : ysz;
    size_t needed = ((size_t)(ureg - (int*)d_ws) + uni) * sizeof(int);

    if (ws_size >= needed) {
        hipMemsetAsync(gbh_u, 0, (size_t)(NBK_U + NBK_M) * sizeof(int), stream);

        bucket_count_kernel<<<(NE / CEC + 255) / 256, 256, 0, stream>>>(
            edge_from, edge_to, gbh_u, gbh_m);
        scan_small_kernel<<<1, 256, 0, stream>>>(gbh_u, bo_u, bcur_u, NBK_U);
        scan_small_kernel<<<1, 256, 0, stream>>>(gbh_m, bo_m, bcur_m, NBK_M);

        // u-side: dest = user (edge_to), src = movie (edge_from)
        partition_kernel<<<(NE / PEC + 255) / 256, 256, 0, stream>>>(
            edge_to, edge_from, bcur_u, stage, NBK_U, VB_U, 0);
        build_kernel<<<NBK_U, 256, 0, stream>>>(stage, bo_u, rp_u, pay_u, NVK_U, VB_U);

        // m-side: dest = movie (edge_from), src = user (edge_to)
        partition_kernel<<<(NE / PEC + 255) / 256, 256, 0, stream>>>(
            edge_from, edge_to, bcur_m, stage, NBK_M, VB_M, 1);
        build_kernel<<<NBK_M, 256, 0, stream>>>(stage, bo_m, rp_m, pay_m, NVK_M, VB_M);

        // inv from rp run-length sums
        inv_u_kernel<<<(NU + 255) / 256, 256, 0, stream>>>(rp_u, inv_u);
        inv_m_kernel<<<(NM + 255) / 256, 256, 0, stream>>>(rp_m, inv_m);

        // prescale (stage is dead now; y overlays it)
        prescale_kernel<<<((size_t)NU * DD + 255) / 256, 256, 0, stream>>>(
            emb_user, inv_u, y_u, NU * DD);
        prescale_kernel<<<((size_t)NM * DD + 255) / 256, 256, 0, stream>>>(
            emb_movie, inv_m, y_m, NM * DD);

        gather_kernel_t<GU, NPH_U><<<NGRP_U / 4, 256, 0, stream>>>(
            rp_u, pay_u, inv_u, y_m, emb_user, res_u);
        gather_kernel_t<GM, NPH_M><<<NGRP_M / 4, 256, 0, stream>>>(
            rp_m, pay_m, inv_m, y_u, emb_movie, res_m);
    } else {
        // ---- fallback: atomic path ----
        float* fdeg_u = (float*)d_ws;
        float* fdeg_m = fdeg_u + NU;
        hipMemsetAsync(res_u, 0, (size_t)(NU + NM) * DD * sizeof(float), stream);
        hipMemsetAsync(fdeg_u, 0, (size_t)(NU + NM) * sizeof(float), stream);
        degree_kernel_f<<<(NE + 255) / 256, 256, 0, stream>>>(edge_from, edge_to, fdeg_m, fdeg_u);
        inv_kernel_f<<<(NU + NM + 255) / 256, 256, 0, stream>>>(fdeg_u, NU + NM);
        agg_kernel_f<<<((size_t)NE * 64 + 255) / 256, 256, 0, stream>>>(
            edge_from, edge_to, fdeg_m, fdeg_u, emb_user, emb_movie, res_u, res_m);
        add_base_kernel_f<<<((NU + NM) * DD + 255) / 256, 256, 0, stream>>>(
            emb_user, emb_movie, res_u, res_m);
    }

    score_kernel<<<((size_t)NL * 64 + 255) / 256, 256, 0, stream>>>(
        label_movie, label_user, res_u, res_m, scores);
}